// Round 1
// baseline (271.860 us; speedup 1.0000x reference)
//
#include <hip/hip_runtime.h>
#include <stdint.h>

typedef unsigned short u16;
typedef __bf16 bf16x8 __attribute__((ext_vector_type(8)));
typedef float f32x4 __attribute__((ext_vector_type(4)));

// fp32 -> bf16 round-to-nearest-even (bit-level, avoids API uncertainty)
__device__ __forceinline__ u16 f2b(float f) {
  unsigned u = __builtin_bit_cast(unsigned, f);
  u += 0x7fffu + ((u >> 16) & 1u);
  return (u16)(u >> 16);
}

// async global->LDS, 16B per lane; LDS dest is wave-uniform base + lane*16
__device__ __forceinline__ void gld_lds16(const void* g, void* l) {
  __builtin_amdgcn_global_load_lds((const __attribute__((address_space(1))) unsigned int*)g,
                                   (__attribute__((address_space(3))) unsigned int*)l,
                                   16, 0, 0);
}

__global__ __launch_bounds__(256) void k_cvt(const float* __restrict__ s,
                                             u16* __restrict__ d, int n4) {
  int i = blockIdx.x * 256 + threadIdx.x;
  if (i >= n4) return;
  float4 v = reinterpret_cast<const float4*>(s)[i];
  ushort4 o;
  o.x = f2b(v.x); o.y = f2b(v.y); o.z = f2b(v.z); o.w = f2b(v.w);
  reinterpret_cast<ushort4*>(d)[i] = o;
}

// C = A(MxK) * B(NxK)^T, bf16 in, K=1024, 128x128 tile, BK=32, 256 thr / 4 waves.
// EPI==1: qkv epilogue (bias, q-scale, scatter to q_ws/k_ws/vt_ws)
// EPI==0: out epilogue (bias, fp32 write to outF)
template <int EPI>
__global__ __launch_bounds__(256) void k_gemm_nt(
    const u16* __restrict__ A, const u16* __restrict__ B, const float* __restrict__ bias,
    float* __restrict__ outF, u16* __restrict__ q_ws, u16* __restrict__ k_ws,
    u16* __restrict__ vt_ws) {
  __shared__ u16 Al[2][4096];
  __shared__ u16 Bl[2][4096];
  const int tid = threadIdx.x;
  const int w = tid >> 6, lane = tid & 63;
  const int wr = w >> 1, wc = w & 1;
  const int lo = lane & 15, hi = lane >> 4;
  const int tm = blockIdx.y, tn = blockIdx.x;
  const size_t arow0 = (size_t)tm * 128;
  const size_t brow0 = (size_t)tn * 128;

  f32x4 acc[4][4] = {};

  const int rr = lane >> 2;
  const int kc = (lane & 3) * 8;

  // prologue stage of k-tile 0
  {
    const int k0 = kc;
    for (int rs = 0; rs < 2; ++rs) {
      int seg = rs * 4 + w;
      gld_lds16(A + (arow0 + seg * 16 + rr) * 1024 + k0, &Al[0][seg * 512 + lane * 8]);
      gld_lds16(B + (brow0 + seg * 16 + rr) * 1024 + k0, &Bl[0][seg * 512 + lane * 8]);
    }
  }
  __syncthreads();
  int cur = 0;
  for (int kb = 0; kb < 32; ++kb) {
    if (kb + 1 < 32) {
      const int k0 = (kb + 1) * 32 + kc;
      for (int rs = 0; rs < 2; ++rs) {
        int seg = rs * 4 + w;
        gld_lds16(A + (arow0 + seg * 16 + rr) * 1024 + k0, &Al[cur ^ 1][seg * 512 + lane * 8]);
        gld_lds16(B + (brow0 + seg * 16 + rr) * 1024 + k0, &Bl[cur ^ 1][seg * 512 + lane * 8]);
      }
    }
    bf16x8 af[4], bfr[4];
#pragma unroll
    for (int m = 0; m < 4; ++m)
      af[m] = *(const bf16x8*)&Al[cur][(wr * 64 + m * 16 + lo) * 32 + hi * 8];
#pragma unroll
    for (int n = 0; n < 4; ++n)
      bfr[n] = *(const bf16x8*)&Bl[cur][(wc * 64 + n * 16 + lo) * 32 + hi * 8];
#pragma unroll
    for (int m = 0; m < 4; ++m)
#pragma unroll
      for (int n = 0; n < 4; ++n)
        acc[m][n] = __builtin_amdgcn_mfma_f32_16x16x32_bf16(af[m], bfr[n], acc[m][n], 0, 0, 0);
    __syncthreads();  // drains vmcnt (staged tile ready) + all waves done with cur
    cur ^= 1;
  }

#pragma unroll
  for (int n = 0; n < 4; ++n) {
    const int col = tn * 128 + wc * 64 + n * 16 + lo;
    const float bb = bias[col];
#pragma unroll
    for (int m = 0; m < 4; ++m) {
#pragma unroll
      for (int r = 0; r < 4; ++r) {
        const int row = tm * 128 + wr * 64 + m * 16 + hi * 4 + r;
        const float val = acc[m][n][r] + bb;
        if (EPI == 0) {
          outF[(size_t)row * 1024 + col] = val;
        } else {
          const int sec = col >> 10, cin = col & 1023;
          const int h = cin >> 6, d = cin & 63;
          const int t = row >> 1, b = row & 1;
          const size_t bh = (size_t)b * 16 + h;
          if (sec == 0)      q_ws[(bh * 2048 + t) * 64 + d] = f2b(val * 0.125f);
          else if (sec == 1) k_ws[(bh * 2048 + t) * 64 + d] = f2b(val);
          else               vt_ws[(bh * 64 + d) * 2048 + t] = f2b(val);
        }
      }
    }
  }
}

// Flash attention fwd: 1 wg = (bh, 64 q-rows); 4 waves x 16 rows; K-tiles of 64.
// Produces bf16 ctx in [T*B][E] layout + rowwise m (max) and 1/l for k_avg.
__global__ __launch_bounds__(256) void k_flash(
    const u16* __restrict__ q_ws, const u16* __restrict__ k_ws, const u16* __restrict__ vt_ws,
    u16* __restrict__ ctx_ws, float* __restrict__ m_ws, float* __restrict__ linv_ws) {
  __shared__ u16 Kl[64 * 72];   // [key][e], padded to 72 to break stride-128B conflicts
  __shared__ u16 Vl[64 * 72];   // [d][key], padded
  __shared__ u16 Pl[4][16 * 72];  // per-wave P tile [qrow][key], padded
  const int tid = threadIdx.x, w = tid >> 6, lane = tid & 63;
  const int lo = lane & 15, hi = lane >> 4;
  const int bh = blockIdx.y;
  const int qb = blockIdx.x * 64;

  const u16* qp = q_ws + ((size_t)bh * 2048 + qb + w * 16 + lo) * 64 + hi * 8;
  bf16x8 qf0 = *(const bf16x8*)qp;
  bf16x8 qf1 = *(const bf16x8*)(qp + 32);

  f32x4 ctx[4] = {};
  float mrow[4], lrow[4];
#pragma unroll
  for (int r = 0; r < 4; ++r) { mrow[r] = -1e30f; lrow[r] = 0.f; }
  const f32x4 zero = {0.f, 0.f, 0.f, 0.f};

  for (int kt = 0; kt < 32; ++kt) {
    const int kbase = kt * 64;
    for (int i = tid; i < 512; i += 256) {
      int r8 = i >> 3, cc = (i & 7) * 8;
      *(uint4*)&Kl[r8 * 72 + cc] =
          *(const uint4*)(k_ws + ((size_t)bh * 2048 + kbase + r8) * 64 + cc);
      *(uint4*)&Vl[r8 * 72 + cc] =
          *(const uint4*)(vt_ws + ((size_t)bh * 64 + r8) * 2048 + kbase + cc);
    }
    __syncthreads();

    f32x4 s[4];
#pragma unroll
    for (int n = 0; n < 4; ++n) {
      const u16* kp = &Kl[(n * 16 + lo) * 72 + hi * 8];
      s[n] = __builtin_amdgcn_mfma_f32_16x16x32_bf16(qf0, *(const bf16x8*)kp, zero, 0, 0, 0);
      s[n] = __builtin_amdgcn_mfma_f32_16x16x32_bf16(qf1, *(const bf16x8*)(kp + 32), s[n], 0, 0, 0);
    }
    float tmax[4];
#pragma unroll
    for (int r = 0; r < 4; ++r)
      tmax[r] = fmaxf(fmaxf(s[0][r], s[1][r]), fmaxf(s[2][r], s[3][r]));
#pragma unroll
    for (int msk = 1; msk < 16; msk <<= 1)
#pragma unroll
      for (int r = 0; r < 4; ++r) tmax[r] = fmaxf(tmax[r], __shfl_xor(tmax[r], msk, 64));
    float sc[4], psum[4];
#pragma unroll
    for (int r = 0; r < 4; ++r) {
      float nm = fmaxf(mrow[r], tmax[r]);
      sc[r] = __expf(mrow[r] - nm);
      mrow[r] = nm;
      psum[r] = 0.f;
    }
#pragma unroll
    for (int n = 0; n < 4; ++n)
#pragma unroll
      for (int r = 0; r < 4; ++r) {
        float p = __expf(s[n][r] - mrow[r]);
        psum[r] += p;
        s[n][r] = p;
      }
#pragma unroll
    for (int msk = 1; msk < 16; msk <<= 1)
#pragma unroll
      for (int r = 0; r < 4; ++r) psum[r] += __shfl_xor(psum[r], msk, 64);
#pragma unroll
    for (int r = 0; r < 4; ++r) lrow[r] = lrow[r] * sc[r] + psum[r];
#pragma unroll
    for (int n = 0; n < 4; ++n)
#pragma unroll
      for (int r = 0; r < 4; ++r) ctx[n][r] *= sc[r];
    // P -> wave-private LDS (D-layout scatter), then re-read as A-fragments
#pragma unroll
    for (int n = 0; n < 4; ++n)
#pragma unroll
      for (int r = 0; r < 4; ++r)
        Pl[w][(hi * 4 + r) * 72 + n * 16 + lo] = f2b(s[n][r]);
    asm volatile("s_waitcnt lgkmcnt(0)" ::: "memory");
    __builtin_amdgcn_sched_barrier(0);
    bf16x8 pa0 = *(const bf16x8*)&Pl[w][lo * 72 + hi * 8];
    bf16x8 pa1 = *(const bf16x8*)&Pl[w][lo * 72 + 32 + hi * 8];
#pragma unroll
    for (int n = 0; n < 4; ++n) {
      const u16* vp = &Vl[(n * 16 + lo) * 72 + hi * 8];
      ctx[n] = __builtin_amdgcn_mfma_f32_16x16x32_bf16(pa0, *(const bf16x8*)vp, ctx[n], 0, 0, 0);
      ctx[n] = __builtin_amdgcn_mfma_f32_16x16x32_bf16(pa1, *(const bf16x8*)(vp + 32), ctx[n], 0, 0, 0);
    }
    __syncthreads();
  }

  const int b = bh >> 4, h = bh & 15;
  float inv[4];
#pragma unroll
  for (int r = 0; r < 4; ++r) inv[r] = 1.0f / lrow[r];
#pragma unroll
  for (int n = 0; n < 4; ++n)
#pragma unroll
    for (int r = 0; r < 4; ++r) {
      const int trow = qb + w * 16 + hi * 4 + r;
      ctx_ws[((size_t)(trow * 2 + b)) * 1024 + h * 64 + n * 16 + lo] = f2b(ctx[n][r] * inv[r]);
    }
  if (lo == 0) {
#pragma unroll
    for (int r = 0; r < 4; ++r) {
      const int trow = qb + w * 16 + hi * 4 + r;
      m_ws[(size_t)bh * 2048 + trow] = mrow[r];
      linv_ws[(size_t)bh * 2048 + trow] = inv[r];
    }
  }
}

// avg_weights: wg owns (b, 64 q-rows, 256 k-cols); loops 16 heads serially
// (deterministic sum), recomputes S via MFMA, p = exp(s-m)*linv, reg-accumulates.
__global__ __launch_bounds__(256) void k_avg(
    const u16* __restrict__ q_ws, const u16* __restrict__ k_ws,
    const float* __restrict__ m_ws, const float* __restrict__ linv_ws,
    float* __restrict__ avg) {
  __shared__ u16 Kl[256 * 72];
  const int tid = threadIdx.x, w = tid >> 6, lane = tid & 63;
  const int lo = lane & 15, hi = lane >> 4;
  const int kbase = blockIdx.x * 256;
  const int qb = blockIdx.y * 64;
  const int b = blockIdx.z;
  const int qrow_base = qb + w * 16 + hi * 4;

  float acc[16][4] = {};
  const f32x4 zero = {0.f, 0.f, 0.f, 0.f};

  for (int h = 0; h < 16; ++h) {
    const int bh = b * 16 + h;
    for (int i = tid; i < 2048; i += 256) {
      int r8 = i >> 3, cc = (i & 7) * 8;
      *(uint4*)&Kl[r8 * 72 + cc] =
          *(const uint4*)(k_ws + ((size_t)bh * 2048 + kbase + r8) * 64 + cc);
    }
    __syncthreads();
    const u16* qp = q_ws + ((size_t)bh * 2048 + qb + w * 16 + lo) * 64 + hi * 8;
    bf16x8 qf0 = *(const bf16x8*)qp;
    bf16x8 qf1 = *(const bf16x8*)(qp + 32);
    float mr[4], li[4];
#pragma unroll
    for (int r = 0; r < 4; ++r) {
      mr[r] = m_ws[(size_t)bh * 2048 + qrow_base + r];
      li[r] = linv_ws[(size_t)bh * 2048 + qrow_base + r];
    }
#pragma unroll
    for (int n = 0; n < 16; ++n) {
      const u16* kp = &Kl[(n * 16 + lo) * 72 + hi * 8];
      f32x4 s = __builtin_amdgcn_mfma_f32_16x16x32_bf16(qf0, *(const bf16x8*)kp, zero, 0, 0, 0);
      s = __builtin_amdgcn_mfma_f32_16x16x32_bf16(qf1, *(const bf16x8*)(kp + 32), s, 0, 0, 0);
#pragma unroll
      for (int r = 0; r < 4; ++r) acc[n][r] += __expf(s[r] - mr[r]) * li[r];
    }
    __syncthreads();
  }
  const float s16 = 1.0f / 16.0f;
#pragma unroll
  for (int n = 0; n < 16; ++n)
#pragma unroll
    for (int r = 0; r < 4; ++r)
      avg[((size_t)(b * 2048 + qrow_base + r)) * 2048 + kbase + n * 16 + lo] = acc[n][r] * s16;
}

extern "C" void kernel_launch(void* const* d_in, const int* in_sizes, int n_in,
                              void* d_out, int out_size, void* d_ws, size_t ws_size,
                              hipStream_t stream) {
  const float* query = (const float*)d_in[0];
  const float* Wqkv  = (const float*)d_in[1];
  const float* bqkv  = (const float*)d_in[2];
  const float* Wo    = (const float*)d_in[3];
  const float* bo    = (const float*)d_in[4];
  float* out = (float*)d_out;
  float* avg = out + (size_t)4096 * 1024;

  char* ws = (char*)d_ws;
  // region A [0,8M): qbf (cvt -> gemm1), then ctx (flash -> gemm3)
  u16* qbf    = (u16*)(ws);
  u16* ctx_ws = (u16*)(ws);
  // region B [8M,14M): wqkvbf (cvt -> gemm1), then m/linv (flash -> avg)
  u16*   wqkvbf  = (u16*)(ws + 8388608);
  float* m_ws    = (float*)(ws + 8388608);
  float* linv_ws = (float*)(ws + 8388608 + 262144);
  u16* wobf  = (u16*)(ws + 14680064);
  u16* q_ws  = (u16*)(ws + 16777216);
  u16* k_ws  = (u16*)(ws + 25165824);
  u16* vt_ws = (u16*)(ws + 33554432);  // ends at 41,943,040 bytes

  k_cvt<<<dim3(4096), dim3(256), 0, stream>>>(query, qbf, 1048576);
  k_cvt<<<dim3(3072), dim3(256), 0, stream>>>(Wqkv, wqkvbf, 786432);
  k_cvt<<<dim3(1024), dim3(256), 0, stream>>>(Wo, wobf, 262144);
  k_gemm_nt<1><<<dim3(24, 32), dim3(256), 0, stream>>>(
      qbf, wqkvbf, bqkv, nullptr, q_ws, k_ws, vt_ws);
  k_flash<<<dim3(32, 32), dim3(256), 0, stream>>>(
      q_ws, k_ws, vt_ws, ctx_ws, m_ws, linv_ws);
  k_avg<<<dim3(8, 32, 2), dim3(256), 0, stream>>>(
      q_ws, k_ws, m_ws, linv_ws, avg);
  k_gemm_nt<0><<<dim3(8, 32), dim3(256), 0, stream>>>(
      ctx_ws, wobf, bo, out, nullptr, nullptr, nullptr);
}

// Round 2
// 216.763 us; speedup vs baseline: 1.2542x; 1.2542x over previous
//
#include <hip/hip_runtime.h>
#include <stdint.h>

typedef unsigned short u16;
typedef __bf16 bf16x8 __attribute__((ext_vector_type(8)));
typedef float f32x4 __attribute__((ext_vector_type(4)));
typedef float f32x16 __attribute__((ext_vector_type(16)));

// fp32 -> bf16 round-to-nearest-even (bit-level)
__device__ __forceinline__ u16 f2b(float f) {
  unsigned u = __builtin_bit_cast(unsigned, f);
  u += 0x7fffu + ((u >> 16) & 1u);
  return (u16)(u >> 16);
}

// async global->LDS, 16B per lane; LDS dest is wave-uniform base + lane*16
__device__ __forceinline__ void gld_lds16(const void* g, void* l) {
  __builtin_amdgcn_global_load_lds((const __attribute__((address_space(1))) unsigned int*)g,
                                   (__attribute__((address_space(3))) unsigned int*)l,
                                   16, 0, 0);
}

__global__ __launch_bounds__(256) void k_cvt(const float* __restrict__ s,
                                             u16* __restrict__ d, int n4) {
  int i = blockIdx.x * 256 + threadIdx.x;
  if (i >= n4) return;
  float4 v = reinterpret_cast<const float4*>(s)[i];
  ushort4 o;
  o.x = f2b(v.x); o.y = f2b(v.y); o.z = f2b(v.z); o.w = f2b(v.w);
  reinterpret_cast<ushort4*>(d)[i] = o;
}

// C = A(MxK) * B(NxK)^T, bf16 in, K=1024, 128x128 tile, BK=32, 256 thr / 4 waves.
// EPI==1: qkv epilogue (bias, q-scale, scatter to q_ws/k_ws/vt_ws)
// EPI==0: out epilogue (bias, fp32 write to outF)
template <int EPI>
__global__ __launch_bounds__(256) void k_gemm_nt(
    const u16* __restrict__ A, const u16* __restrict__ B, const float* __restrict__ bias,
    float* __restrict__ outF, u16* __restrict__ q_ws, u16* __restrict__ k_ws,
    u16* __restrict__ vt_ws) {
  __shared__ u16 Al[2][4096];
  __shared__ u16 Bl[2][4096];
  const int tid = threadIdx.x;
  const int w = tid >> 6, lane = tid & 63;
  const int wr = w >> 1, wc = w & 1;
  const int lo = lane & 15, hi = lane >> 4;
  const int tm = blockIdx.y, tn = blockIdx.x;
  const size_t arow0 = (size_t)tm * 128;
  const size_t brow0 = (size_t)tn * 128;

  f32x4 acc[4][4] = {};

  const int rr = lane >> 2;
  const int kc = (lane & 3) * 8;

  // prologue stage of k-tile 0
  {
    const int k0 = kc;
    for (int rs = 0; rs < 2; ++rs) {
      int seg = rs * 4 + w;
      gld_lds16(A + (arow0 + seg * 16 + rr) * 1024 + k0, &Al[0][seg * 512 + lane * 8]);
      gld_lds16(B + (brow0 + seg * 16 + rr) * 1024 + k0, &Bl[0][seg * 512 + lane * 8]);
    }
  }
  __syncthreads();
  int cur = 0;
  for (int kb = 0; kb < 32; ++kb) {
    if (kb + 1 < 32) {
      const int k0 = (kb + 1) * 32 + kc;
      for (int rs = 0; rs < 2; ++rs) {
        int seg = rs * 4 + w;
        gld_lds16(A + (arow0 + seg * 16 + rr) * 1024 + k0, &Al[cur ^ 1][seg * 512 + lane * 8]);
        gld_lds16(B + (brow0 + seg * 16 + rr) * 1024 + k0, &Bl[cur ^ 1][seg * 512 + lane * 8]);
      }
    }
    bf16x8 af[4], bfr[4];
#pragma unroll
    for (int m = 0; m < 4; ++m)
      af[m] = *(const bf16x8*)&Al[cur][(wr * 64 + m * 16 + lo) * 32 + hi * 8];
#pragma unroll
    for (int n = 0; n < 4; ++n)
      bfr[n] = *(const bf16x8*)&Bl[cur][(wc * 64 + n * 16 + lo) * 32 + hi * 8];
#pragma unroll
    for (int m = 0; m < 4; ++m)
#pragma unroll
      for (int n = 0; n < 4; ++n)
        acc[m][n] = __builtin_amdgcn_mfma_f32_16x16x32_bf16(af[m], bfr[n], acc[m][n], 0, 0, 0);
    __syncthreads();  // drains vmcnt (staged tile ready) + all waves done with cur
    cur ^= 1;
  }

#pragma unroll
  for (int n = 0; n < 4; ++n) {
    const int col = tn * 128 + wc * 64 + n * 16 + lo;
    const float bb = bias[col];
#pragma unroll
    for (int m = 0; m < 4; ++m) {
#pragma unroll
      for (int r = 0; r < 4; ++r) {
        const int row = tm * 128 + wr * 64 + m * 16 + hi * 4 + r;
        const float val = acc[m][n][r] + bb;
        if (EPI == 0) {
          outF[(size_t)row * 1024 + col] = val;
        } else {
          const int sec = col >> 10, cin = col & 1023;
          const int h = cin >> 6, d = cin & 63;
          const int t = row >> 1, b = row & 1;
          const size_t bh = (size_t)b * 16 + h;
          if (sec == 0)      q_ws[(bh * 2048 + t) * 64 + d] = f2b(val * 0.125f);
          else if (sec == 1) k_ws[(bh * 2048 + t) * 64 + d] = f2b(val);
          else {
            // store V^T with key index bit2<->bit3 swapped so flash PV A-frags
            // are single contiguous 16B LDS reads matching the 32x32 C-layout.
            const int tp = (t & ~12) | ((t & 4) << 1) | ((t & 8) >> 1);
            vt_ws[(bh * 64 + d) * 2048 + tp] = f2b(val);
          }
        }
      }
    }
  }
}

// Flash attention fwd, swapped-QK^T 32x32 structure (m214-style).
// wg = 256 thr = 4 warps; warp owns 32 q rows; wg covers 128 q rows.
// Per KV-tile (64 keys): S^T = mfma32x32(K, Q^T) -> lane-local softmax for one
// query -> P^T packed in-register (no cross-lane) -> ctx^T += mfma32x32(V^T, P^T).
__global__ __launch_bounds__(256) void k_flash(
    const u16* __restrict__ q_ws, const u16* __restrict__ k_ws, const u16* __restrict__ vt_ws,
    u16* __restrict__ ctx_ws, float* __restrict__ m_ws, float* __restrict__ linv_ws) {
  __shared__ __align__(16) u16 KVl[8192];  // [0,4096): K [64 key][64 d]; [4096,8192): V^T [64 d][64 key'] — both XOR-swizzled
  u16* Kl = KVl;
  u16* Vl = KVl + 4096;
  const int tid = threadIdx.x, w = tid >> 6, lane = tid & 63;
  const int h = lane >> 5, l31 = lane & 31, l7 = lane & 7;
  const int bh = blockIdx.y;
  const int b = bh >> 4, head = bh & 15;
  const int qbase = blockIdx.x * 128;
  const int qrow = qbase + w * 32 + l31;

  // hoist Q fragments (B-operand): qf[j] = Q[qrow][j*16 + h*8 .. +7]
  bf16x8 qf[4];
#pragma unroll
  for (int j = 0; j < 4; ++j)
    qf[j] = *(const bf16x8*)(q_ws + ((size_t)bh * 2048 + qrow) * 64 + j * 16 + h * 8);

  // staging: 2 K-chunks + 2 V-chunks of 16B per thread, swizzled LDS dest
  const int c0 = tid, c1 = tid + 256;
  const int r0 = c0 >> 3, cc0 = c0 & 7;
  const int r1 = c1 >> 3, cc1 = c1 & 7;
  const u16* kg0 = k_ws + ((size_t)bh * 2048 + r0) * 64 + cc0 * 8;
  const u16* kg1 = k_ws + ((size_t)bh * 2048 + r1) * 64 + cc1 * 8;
  const u16* vg0 = vt_ws + ((size_t)bh * 64 + r0) * 2048 + cc0 * 8;
  const u16* vg1 = vt_ws + ((size_t)bh * 64 + r1) * 2048 + cc1 * 8;
  char* kl0 = (char*)Kl + r0 * 128 + ((cc0 ^ (r0 & 7)) * 16);
  char* kl1 = (char*)Kl + r1 * 128 + ((cc1 ^ (r1 & 7)) * 16);
  char* vl0 = (char*)Vl + r0 * 128 + ((cc0 ^ (r0 & 7)) * 16);
  char* vl1 = (char*)Vl + r1 * 128 + ((cc1 ^ (r1 & 7)) * 16);

  f32x16 ca0 = {}, ca1 = {};
  float mrow = -1e30f, lrow = 0.f;

  // T14 async-stage: tile-0 loads issued before the loop
  uint4 ka = *(const uint4*)kg0;
  uint4 kb = *(const uint4*)kg1;
  uint4 va = *(const uint4*)vg0;
  uint4 vb = *(const uint4*)vg1;

  for (int kt = 0; kt < 32; ++kt) {
    __syncthreads();  // previous tile's LDS reads done
    *(uint4*)kl0 = ka; *(uint4*)kl1 = kb;
    *(uint4*)vl0 = va; *(uint4*)vl1 = vb;
    if (kt < 31) {  // issue next tile's loads; latency hides under compute
      ka = *(const uint4*)(kg0 + (size_t)(kt + 1) * 4096);
      kb = *(const uint4*)(kg1 + (size_t)(kt + 1) * 4096);
      va = *(const uint4*)(vg0 + (kt + 1) * 64);
      vb = *(const uint4*)(vg1 + (kt + 1) * 64);
    }
    __syncthreads();  // staged tile visible

    // QK^T swapped: st_tau holds S^T[tau*32 + rho(reg,h)][q = l31]
    f32x16 st0 = {}, st1 = {};
#pragma unroll
    for (int j = 0; j < 4; ++j) {
      bf16x8 k0 = *(const bf16x8*)((const char*)Kl + l31 * 128 + (((2 * j + h) ^ l7) * 16));
      bf16x8 k1 = *(const bf16x8*)((const char*)Kl + (32 + l31) * 128 + (((2 * j + h) ^ l7) * 16));
      st0 = __builtin_amdgcn_mfma_f32_32x32x16_bf16(k0, qf[j], st0, 0, 0, 0);
      st1 = __builtin_amdgcn_mfma_f32_32x32x16_bf16(k1, qf[j], st1, 0, 0, 0);
    }

    // in-register online softmax (lane pair L <-> L+32 hold complementary keys of same q)
    float pm = st0[0];
#pragma unroll
    for (int r = 1; r < 16; ++r) pm = fmaxf(pm, st0[r]);
#pragma unroll
    for (int r = 0; r < 16; ++r) pm = fmaxf(pm, st1[r]);
    pm = fmaxf(pm, __shfl_xor(pm, 32, 64));
    const float nm = fmaxf(mrow, pm);
    const float sc = __expf(mrow - nm);
    mrow = nm;
    float ps = 0.f;
#pragma unroll
    for (int r = 0; r < 16; ++r) { float p = __expf(st0[r] - nm); st0[r] = p; ps += p; }
#pragma unroll
    for (int r = 0; r < 16; ++r) { float p = __expf(st1[r] - nm); st1[r] = p; ps += p; }
    ps += __shfl_xor(ps, 32, 64);
    lrow = lrow * sc + ps;
#pragma unroll
    for (int r = 0; r < 16; ++r) { ca0[r] *= sc; ca1[r] *= sc; }

    // pack P^T -> bf16 B-frags; slot i of (tau,kap) = p_tau[kap*8+i]; zero cross-lane
    union { bf16x8 v; u16 s[8]; } pb00, pb01, pb10, pb11;
#pragma unroll
    for (int i = 0; i < 8; ++i) {
      pb00.s[i] = f2b(st0[i]);
      pb01.s[i] = f2b(st0[8 + i]);
      pb10.s[i] = f2b(st1[i]);
      pb11.s[i] = f2b(st1[8 + i]);
    }

    // PV: ctx^T[dh*32 + rho][q] += V^T x P^T  (V key order pre-permuted bit2<->3)
#pragma unroll
    for (int t2 = 0; t2 < 2; ++t2)
#pragma unroll
      for (int kp = 0; kp < 2; ++kp) {
        const int ch = (4 * t2 + 2 * kp + h) ^ l7;
        bf16x8 v0 = *(const bf16x8*)((const char*)Vl + l31 * 128 + ch * 16);
        bf16x8 v1 = *(const bf16x8*)((const char*)Vl + (32 + l31) * 128 + ch * 16);
        const bf16x8 pv = (t2 == 0) ? (kp == 0 ? pb00.v : pb01.v) : (kp == 0 ? pb10.v : pb11.v);
        ca0 = __builtin_amdgcn_mfma_f32_32x32x16_bf16(v0, pv, ca0, 0, 0, 0);
        ca1 = __builtin_amdgcn_mfma_f32_32x32x16_bf16(v1, pv, ca1, 0, 0, 0);
      }
  }

  const float inv = 1.0f / lrow;
  if (lane < 32) {
    m_ws[(size_t)bh * 2048 + qrow] = mrow;
    linv_ws[(size_t)bh * 2048 + qrow] = inv;
  }

  // epilogue: transpose ctx^T -> ctx via reused LDS (warp-private 4KB region)
  __syncthreads();  // all warps done with K/V tiles
  u16* tw = KVl + w * 2048;
#pragma unroll
  for (int r = 0; r < 16; ++r) {
    const int d0 = (r & 3) + 8 * (r >> 2) + 4 * h;
    const int d1 = 32 + d0;
    *(u16*)((char*)tw + l31 * 128 + ((2 * d0) ^ (l7 << 4))) = f2b(ca0[r] * inv);
    *(u16*)((char*)tw + l31 * 128 + ((2 * d1) ^ (l7 << 4))) = f2b(ca1[r] * inv);
  }
  __syncthreads();
#pragma unroll
  for (int it = 0; it < 4; ++it) {
    const int row = it * 8 + (lane >> 3);
    uint4 val = *(const uint4*)((const char*)tw + row * 128 + (((lane & 7) ^ (row & 7)) * 16));
    const int q = qbase + w * 32 + row;
    *(uint4*)(ctx_ws + ((size_t)(q * 2 + b)) * 1024 + head * 64 + (lane & 7) * 8) = val;
  }
}

// avg_weights: wg owns (b, 64 q-rows, 256 k-cols); loops 16 heads serially
// (deterministic sum), recomputes S via MFMA, p = exp(s-m)*linv, reg-accumulates.
__global__ __launch_bounds__(256) void k_avg(
    const u16* __restrict__ q_ws, const u16* __restrict__ k_ws,
    const float* __restrict__ m_ws, const float* __restrict__ linv_ws,
    float* __restrict__ avg) {
  __shared__ u16 Kl[256 * 72];
  const int tid = threadIdx.x, w = tid >> 6, lane = tid & 63;
  const int lo = lane & 15, hi = lane >> 4;
  const int kbase = blockIdx.x * 256;
  const int qb = blockIdx.y * 64;
  const int b = blockIdx.z;
  const int qrow_base = qb + w * 16 + hi * 4;

  float acc[16][4] = {};
  const f32x4 zero = {0.f, 0.f, 0.f, 0.f};

  for (int h = 0; h < 16; ++h) {
    const int bh = b * 16 + h;
    for (int i = tid; i < 2048; i += 256) {
      int r8 = i >> 3, cc = (i & 7) * 8;
      *(uint4*)&Kl[r8 * 72 + cc] =
          *(const uint4*)(k_ws + ((size_t)bh * 2048 + kbase + r8) * 64 + cc);
    }
    __syncthreads();
    const u16* qp = q_ws + ((size_t)bh * 2048 + qb + w * 16 + lo) * 64 + hi * 8;
    bf16x8 qf0 = *(const bf16x8*)qp;
    bf16x8 qf1 = *(const bf16x8*)(qp + 32);
    float mr[4], li[4];
#pragma unroll
    for (int r = 0; r < 4; ++r) {
      mr[r] = m_ws[(size_t)bh * 2048 + qrow_base + r];
      li[r] = linv_ws[(size_t)bh * 2048 + qrow_base + r];
    }
#pragma unroll
    for (int n = 0; n < 16; ++n) {
      const u16* kp = &Kl[(n * 16 + lo) * 72 + hi * 8];
      f32x4 s = __builtin_amdgcn_mfma_f32_16x16x32_bf16(qf0, *(const bf16x8*)kp, zero, 0, 0, 0);
      s = __builtin_amdgcn_mfma_f32_16x16x32_bf16(qf1, *(const bf16x8*)(kp + 32), s, 0, 0, 0);
#pragma unroll
      for (int r = 0; r < 4; ++r) acc[n][r] += __expf(s[r] - mr[r]) * li[r];
    }
    __syncthreads();
  }
  const float s16 = 1.0f / 16.0f;
#pragma unroll
  for (int n = 0; n < 16; ++n)
#pragma unroll
    for (int r = 0; r < 4; ++r)
      avg[((size_t)(b * 2048 + qrow_base + r)) * 2048 + kbase + n * 16 + lo] = acc[n][r] * s16;
}

extern "C" void kernel_launch(void* const* d_in, const int* in_sizes, int n_in,
                              void* d_out, int out_size, void* d_ws, size_t ws_size,
                              hipStream_t stream) {
  const float* query = (const float*)d_in[0];
  const float* Wqkv  = (const float*)d_in[1];
  const float* bqkv  = (const float*)d_in[2];
  const float* Wo    = (const float*)d_in[3];
  const float* bo    = (const float*)d_in[4];
  float* out = (float*)d_out;
  float* avg = out + (size_t)4096 * 1024;

  char* ws = (char*)d_ws;
  // region A [0,8M): qbf (cvt -> gemm1), then ctx (flash -> gemm3)
  u16* qbf    = (u16*)(ws);
  u16* ctx_ws = (u16*)(ws);
  // region B [8M,14M): wqkvbf (cvt -> gemm1), then m/linv (flash -> avg)
  u16*   wqkvbf  = (u16*)(ws + 8388608);
  float* m_ws    = (float*)(ws + 8388608);
  float* linv_ws = (float*)(ws + 8388608 + 262144);
  u16* wobf  = (u16*)(ws + 14680064);
  u16* q_ws  = (u16*)(ws + 16777216);
  u16* k_ws  = (u16*)(ws + 25165824);
  u16* vt_ws = (u16*)(ws + 33554432);  // ends at 41,943,040 bytes

  k_cvt<<<dim3(4096), dim3(256), 0, stream>>>(query, qbf, 1048576);
  k_cvt<<<dim3(3072), dim3(256), 0, stream>>>(Wqkv, wqkvbf, 786432);
  k_cvt<<<dim3(1024), dim3(256), 0, stream>>>(Wo, wobf, 262144);
  k_gemm_nt<1><<<dim3(24, 32), dim3(256), 0, stream>>>(
      qbf, wqkvbf, bqkv, nullptr, q_ws, k_ws, vt_ws);
  k_flash<<<dim3(16, 32), dim3(256), 0, stream>>>(
      q_ws, k_ws, vt_ws, ctx_ws, m_ws, linv_ws);
  k_avg<<<dim3(8, 32, 2), dim3(256), 0, stream>>>(
      q_ws, k_ws, m_ws, linv_ws, avg);
  k_gemm_nt<0><<<dim3(8, 32), dim3(256), 0, stream>>>(
      ctx_ws, wobf, bo, out, nullptr, nullptr, nullptr);
}

// Round 3
// 198.079 us; speedup vs baseline: 1.3725x; 1.0943x over previous
//
#include <hip/hip_runtime.h>
#include <stdint.h>

typedef unsigned short u16;
typedef __bf16 bf16x8 __attribute__((ext_vector_type(8)));
typedef float f32x4 __attribute__((ext_vector_type(4)));
typedef float f32x16 __attribute__((ext_vector_type(16)));

// fp32 -> bf16 round-to-nearest-even (bit-level)
__device__ __forceinline__ u16 f2b(float f) {
  unsigned u = __builtin_bit_cast(unsigned, f);
  u += 0x7fffu + ((u >> 16) & 1u);
  return (u16)(u >> 16);
}

__device__ __forceinline__ float fexp2(float x) { return __builtin_amdgcn_exp2f(x); }

// async global->LDS, 16B per lane; LDS dest is wave-uniform base + lane*16
__device__ __forceinline__ void gld_lds16(const void* g, void* l) {
  __builtin_amdgcn_global_load_lds((const __attribute__((address_space(1))) unsigned int*)g,
                                   (__attribute__((address_space(3))) unsigned int*)l,
                                   16, 0, 0);
}

__global__ __launch_bounds__(256) void k_cvt(const float* __restrict__ s,
                                             u16* __restrict__ d, int n4) {
  int i = blockIdx.x * 256 + threadIdx.x;
  if (i >= n4) return;
  float4 v = reinterpret_cast<const float4*>(s)[i];
  ushort4 o;
  o.x = f2b(v.x); o.y = f2b(v.y); o.z = f2b(v.z); o.w = f2b(v.w);
  reinterpret_cast<ushort4*>(d)[i] = o;
}

// C = A(MxK) * B(NxK)^T, bf16 in, K=1024, 128x128 tile, BK=32, 256 thr / 4 waves.
// EPI==1: qkv epilogue (bias, q-scale incl. log2e, scatter to q_ws/k_ws/vt_ws)
// EPI==0: out epilogue (bias, fp32 write to outF)
template <int EPI>
__global__ __launch_bounds__(256) void k_gemm_nt(
    const u16* __restrict__ A, const u16* __restrict__ B, const float* __restrict__ bias,
    float* __restrict__ outF, u16* __restrict__ q_ws, u16* __restrict__ k_ws,
    u16* __restrict__ vt_ws) {
  __shared__ u16 Al[2][4096];
  __shared__ u16 Bl[2][4096];
  const int tid = threadIdx.x;
  const int w = tid >> 6, lane = tid & 63;
  const int wr = w >> 1, wc = w & 1;
  const int lo = lane & 15, hi = lane >> 4;
  const int tm = blockIdx.y, tn = blockIdx.x;
  const size_t arow0 = (size_t)tm * 128;
  const size_t brow0 = (size_t)tn * 128;

  f32x4 acc[4][4] = {};

  const int rr = lane >> 2;
  const int kc = (lane & 3) * 8;

  // prologue stage of k-tile 0
  {
    const int k0 = kc;
    for (int rs = 0; rs < 2; ++rs) {
      int seg = rs * 4 + w;
      gld_lds16(A + (arow0 + seg * 16 + rr) * 1024 + k0, &Al[0][seg * 512 + lane * 8]);
      gld_lds16(B + (brow0 + seg * 16 + rr) * 1024 + k0, &Bl[0][seg * 512 + lane * 8]);
    }
  }
  __syncthreads();
  int cur = 0;
  for (int kb = 0; kb < 32; ++kb) {
    if (kb + 1 < 32) {
      const int k0 = (kb + 1) * 32 + kc;
      for (int rs = 0; rs < 2; ++rs) {
        int seg = rs * 4 + w;
        gld_lds16(A + (arow0 + seg * 16 + rr) * 1024 + k0, &Al[cur ^ 1][seg * 512 + lane * 8]);
        gld_lds16(B + (brow0 + seg * 16 + rr) * 1024 + k0, &Bl[cur ^ 1][seg * 512 + lane * 8]);
      }
    }
    bf16x8 af[4], bfr[4];
#pragma unroll
    for (int m = 0; m < 4; ++m)
      af[m] = *(const bf16x8*)&Al[cur][(wr * 64 + m * 16 + lo) * 32 + hi * 8];
#pragma unroll
    for (int n = 0; n < 4; ++n)
      bfr[n] = *(const bf16x8*)&Bl[cur][(wc * 64 + n * 16 + lo) * 32 + hi * 8];
#pragma unroll
    for (int m = 0; m < 4; ++m)
#pragma unroll
      for (int n = 0; n < 4; ++n)
        acc[m][n] = __builtin_amdgcn_mfma_f32_16x16x32_bf16(af[m], bfr[n], acc[m][n], 0, 0, 0);
    __syncthreads();  // drains vmcnt (staged tile ready) + all waves done with cur
    cur ^= 1;
  }

  if (EPI == 0) {
#pragma unroll
    for (int n = 0; n < 4; ++n) {
      const int col = tn * 128 + wc * 64 + n * 16 + lo;
      const float bb = bias[col];
#pragma unroll
      for (int m = 0; m < 4; ++m)
#pragma unroll
        for (int r = 0; r < 4; ++r) {
          const int row = tm * 128 + wr * 64 + m * 16 + hi * 4 + r;
          outF[(size_t)row * 1024 + col] = acc[m][n][r] + bb;
        }
    }
  } else {
    const int sec = tn >> 3;  // block-uniform: 0=q, 1=k, 2=v
#pragma unroll
    for (int n = 0; n < 4; ++n) {
      const int cin = (tn & 7) * 128 + wc * 64 + n * 16 + lo;
      const int h = cin >> 6, d = cin & 63;
      const float bb = bias[sec * 1024 + cin];
#pragma unroll
      for (int m = 0; m < 4; ++m) {
        const int rowb = tm * 128 + wr * 64 + m * 16 + hi * 4;
        const int t0 = rowb >> 1;  // always even
        const float v0 = acc[m][n][0] + bb, v1 = acc[m][n][1] + bb;
        const float v2 = acc[m][n][2] + bb, v3 = acc[m][n][3] + bb;
        if (sec == 0) {
          // q: scale by 1/sqrt(64) * log2(e) so softmax runs in exp2 domain
          const float s = 0.18033688f;
          q_ws[(((size_t)h * 2048 + t0) * 64) + d]            = f2b(v0 * s);   // b=0
          q_ws[(((size_t)(16 + h) * 2048 + t0) * 64) + d]     = f2b(v1 * s);   // b=1
          q_ws[(((size_t)h * 2048 + t0 + 1) * 64) + d]        = f2b(v2 * s);
          q_ws[(((size_t)(16 + h) * 2048 + t0 + 1) * 64) + d] = f2b(v3 * s);
        } else if (sec == 1) {
          k_ws[(((size_t)h * 2048 + t0) * 64) + d]            = f2b(v0);
          k_ws[(((size_t)(16 + h) * 2048 + t0) * 64) + d]     = f2b(v1);
          k_ws[(((size_t)h * 2048 + t0 + 1) * 64) + d]        = f2b(v2);
          k_ws[(((size_t)(16 + h) * 2048 + t0 + 1) * 64) + d] = f2b(v3);
        } else {
          // V^T with key index bit2<->bit3 swapped (matches flash PV layout).
          // t0 even => swap(t0+1) == swap(t0)+1 => paired 4B stores.
          const int tp0 = (t0 & ~12) | ((t0 & 4) << 1) | ((t0 & 8) >> 1);
          ushort2 p0, p1;
          p0.x = f2b(v0); p0.y = f2b(v2);
          p1.x = f2b(v1); p1.y = f2b(v3);
          *(ushort2*)(vt_ws + ((size_t)h * 64 + d) * 2048 + tp0) = p0;
          *(ushort2*)(vt_ws + ((size_t)(16 + h) * 64 + d) * 2048 + tp0) = p1;
        }
      }
    }
  }
}

// Flash attention fwd, swapped-QK^T 32x32 structure (m214-style), exp2 domain.
// wg = 256 thr = 4 warps; warp owns 32 q rows; wg covers 128 q rows.
__global__ __launch_bounds__(256) void k_flash(
    const u16* __restrict__ q_ws, const u16* __restrict__ k_ws, const u16* __restrict__ vt_ws,
    u16* __restrict__ ctx_ws, float* __restrict__ m_ws, float* __restrict__ linv_ws) {
  __shared__ __align__(16) u16 KVl[8192];  // [0,4096): K [64 key][64 d]; [4096,8192): V^T — XOR-swizzled
  u16* Kl = KVl;
  u16* Vl = KVl + 4096;
  const int tid = threadIdx.x, w = tid >> 6, lane = tid & 63;
  const int h = lane >> 5, l31 = lane & 31, l7 = lane & 7;
  const int bh = blockIdx.y;
  const int b = bh >> 4, head = bh & 15;
  const int qbase = blockIdx.x * 128;
  const int qrow = qbase + w * 32 + l31;

  // hoist Q fragments (B-operand): qf[j] = Q[qrow][j*16 + h*8 .. +7]
  bf16x8 qf[4];
#pragma unroll
  for (int j = 0; j < 4; ++j)
    qf[j] = *(const bf16x8*)(q_ws + ((size_t)bh * 2048 + qrow) * 64 + j * 16 + h * 8);

  // staging: 2 K-chunks + 2 V-chunks of 16B per thread, swizzled LDS dest
  const int c0 = tid, c1 = tid + 256;
  const int r0 = c0 >> 3, cc0 = c0 & 7;
  const int r1 = c1 >> 3, cc1 = c1 & 7;
  const u16* kg0 = k_ws + ((size_t)bh * 2048 + r0) * 64 + cc0 * 8;
  const u16* kg1 = k_ws + ((size_t)bh * 2048 + r1) * 64 + cc1 * 8;
  const u16* vg0 = vt_ws + ((size_t)bh * 64 + r0) * 2048 + cc0 * 8;
  const u16* vg1 = vt_ws + ((size_t)bh * 64 + r1) * 2048 + cc1 * 8;
  char* kl0 = (char*)Kl + r0 * 128 + ((cc0 ^ (r0 & 7)) * 16);
  char* kl1 = (char*)Kl + r1 * 128 + ((cc1 ^ (r1 & 7)) * 16);
  char* vl0 = (char*)Vl + r0 * 128 + ((cc0 ^ (r0 & 7)) * 16);
  char* vl1 = (char*)Vl + r1 * 128 + ((cc1 ^ (r1 & 7)) * 16);

  f32x16 ca0 = {}, ca1 = {};
  float mrow = -1e30f, lrow = 0.f;

  // T14 async-stage: tile-0 loads issued before the loop
  uint4 ka = *(const uint4*)kg0;
  uint4 kb = *(const uint4*)kg1;
  uint4 va = *(const uint4*)vg0;
  uint4 vb = *(const uint4*)vg1;

  for (int kt = 0; kt < 32; ++kt) {
    __syncthreads();  // previous tile's LDS reads done
    *(uint4*)kl0 = ka; *(uint4*)kl1 = kb;
    *(uint4*)vl0 = va; *(uint4*)vl1 = vb;
    if (kt < 31) {  // issue next tile's loads; latency hides under compute
      ka = *(const uint4*)(kg0 + (size_t)(kt + 1) * 4096);
      kb = *(const uint4*)(kg1 + (size_t)(kt + 1) * 4096);
      va = *(const uint4*)(vg0 + (kt + 1) * 64);
      vb = *(const uint4*)(vg1 + (kt + 1) * 64);
    }
    __syncthreads();  // staged tile visible

    // QK^T swapped: st holds S^T[key][q = l31] in exp2 domain
    f32x16 st0 = {}, st1 = {};
#pragma unroll
    for (int j = 0; j < 4; ++j) {
      bf16x8 k0 = *(const bf16x8*)((const char*)Kl + l31 * 128 + (((2 * j + h) ^ l7) * 16));
      bf16x8 k1 = *(const bf16x8*)((const char*)Kl + (32 + l31) * 128 + (((2 * j + h) ^ l7) * 16));
      st0 = __builtin_amdgcn_mfma_f32_32x32x16_bf16(k0, qf[j], st0, 0, 0, 0);
      st1 = __builtin_amdgcn_mfma_f32_32x32x16_bf16(k1, qf[j], st1, 0, 0, 0);
    }

    // tree max (depth 5, max3-fusable)
    float t8[8];
#pragma unroll
    for (int r = 0; r < 8; ++r)
      t8[r] = fmaxf(fmaxf(st0[r], st0[r + 8]), fmaxf(st1[r], st1[r + 8]));
    float t4a = fmaxf(t8[0], t8[4]), t4b = fmaxf(t8[1], t8[5]);
    float t4c = fmaxf(t8[2], t8[6]), t4d = fmaxf(t8[3], t8[7]);
    float pm = fmaxf(fmaxf(t4a, t4b), fmaxf(t4c, t4d));
    pm = fmaxf(pm, __shfl_xor(pm, 32, 64));

    // T13 defer-max: rescale only when the running max grows by > 8 (log2 units)
    if (!__all(pm <= mrow + 8.0f)) {
      const float nm = fmaxf(mrow, pm);
      const float sc = fexp2(mrow - nm);
      mrow = nm;
      lrow *= sc;
#pragma unroll
      for (int r = 0; r < 16; ++r) { ca0[r] *= sc; ca1[r] *= sc; }
    }

    float ps = 0.f;
#pragma unroll
    for (int r = 0; r < 16; ++r) { float p = fexp2(st0[r] - mrow); st0[r] = p; ps += p; }
#pragma unroll
    for (int r = 0; r < 16; ++r) { float p = fexp2(st1[r] - mrow); st1[r] = p; ps += p; }
    ps += __shfl_xor(ps, 32, 64);
    lrow += ps;

    // pack P^T -> bf16 B-frags (native casts -> v_cvt_pk_bf16_f32); zero cross-lane
    bf16x8 pb00, pb01, pb10, pb11;
#pragma unroll
    for (int i = 0; i < 8; ++i) {
      pb00[i] = (__bf16)st0[i];
      pb01[i] = (__bf16)st0[8 + i];
      pb10[i] = (__bf16)st1[i];
      pb11[i] = (__bf16)st1[8 + i];
    }

    // PV: ctx^T[dh*32 + rho][q] += V^T x P^T  (V key order pre-permuted bit2<->3)
#pragma unroll
    for (int t2 = 0; t2 < 2; ++t2)
#pragma unroll
      for (int kp = 0; kp < 2; ++kp) {
        const int ch = (4 * t2 + 2 * kp + h) ^ l7;
        bf16x8 v0 = *(const bf16x8*)((const char*)Vl + l31 * 128 + ch * 16);
        bf16x8 v1 = *(const bf16x8*)((const char*)Vl + (32 + l31) * 128 + ch * 16);
        const bf16x8 pv = (t2 == 0) ? (kp == 0 ? pb00 : pb01) : (kp == 0 ? pb10 : pb11);
        ca0 = __builtin_amdgcn_mfma_f32_32x32x16_bf16(v0, pv, ca0, 0, 0, 0);
        ca1 = __builtin_amdgcn_mfma_f32_32x32x16_bf16(v1, pv, ca1, 0, 0, 0);
      }
  }

  const float inv = 1.0f / lrow;
  if (lane < 32) {
    m_ws[(size_t)bh * 2048 + qrow] = mrow;
    linv_ws[(size_t)bh * 2048 + qrow] = inv;
  }

  // epilogue: transpose ctx^T -> ctx via reused LDS (warp-private 4KB region)
  __syncthreads();  // all warps done with K/V tiles
  u16* tw = KVl + w * 2048;
#pragma unroll
  for (int r = 0; r < 16; ++r) {
    const int d0 = (r & 3) + 8 * (r >> 2) + 4 * h;
    const int d1 = 32 + d0;
    *(u16*)((char*)tw + l31 * 128 + ((2 * d0) ^ (l7 << 4))) = f2b(ca0[r] * inv);
    *(u16*)((char*)tw + l31 * 128 + ((2 * d1) ^ (l7 << 4))) = f2b(ca1[r] * inv);
  }
  __syncthreads();
#pragma unroll
  for (int it = 0; it < 4; ++it) {
    const int row = it * 8 + (lane >> 3);
    uint4 val = *(const uint4*)((const char*)tw + row * 128 + (((lane & 7) ^ (row & 7)) * 16));
    const int q = qbase + w * 32 + row;
    *(uint4*)(ctx_ws + ((size_t)(q * 2 + b)) * 1024 + head * 64 + (lane & 7) * 8) = val;
  }
}

// avg_weights: wg owns (b, 64 q-rows, 256 k-cols); loops 16 heads serially
// (deterministic sum), recomputes S via MFMA (exp2 domain), reg-accumulates.
__global__ __launch_bounds__(256) void k_avg(
    const u16* __restrict__ q_ws, const u16* __restrict__ k_ws,
    const float* __restrict__ m_ws, const float* __restrict__ linv_ws,
    float* __restrict__ avg) {
  __shared__ u16 Kl[256 * 72];
  const int tid = threadIdx.x, w = tid >> 6, lane = tid & 63;
  const int lo = lane & 15, hi = lane >> 4;
  const int kbase = blockIdx.x * 256;
  const int qb = blockIdx.y * 64;
  const int b = blockIdx.z;
  const int qrow_base = qb + w * 16 + hi * 4;

  float acc[16][4] = {};
  const f32x4 zero = {0.f, 0.f, 0.f, 0.f};

  for (int h = 0; h < 16; ++h) {
    const int bh = b * 16 + h;
    for (int i = tid; i < 2048; i += 256) {
      int r8 = i >> 3, cc = (i & 7) * 8;
      *(uint4*)&Kl[r8 * 72 + cc] =
          *(const uint4*)(k_ws + ((size_t)bh * 2048 + kbase + r8) * 64 + cc);
    }
    __syncthreads();
    const u16* qp = q_ws + ((size_t)bh * 2048 + qb + w * 16 + lo) * 64 + hi * 8;
    bf16x8 qf0 = *(const bf16x8*)qp;
    bf16x8 qf1 = *(const bf16x8*)(qp + 32);
    float mr[4], li[4];
#pragma unroll
    for (int r = 0; r < 4; ++r) {
      mr[r] = m_ws[(size_t)bh * 2048 + qrow_base + r];
      li[r] = linv_ws[(size_t)bh * 2048 + qrow_base + r];
    }
#pragma unroll
    for (int n = 0; n < 16; ++n) {
      const u16* kp = &Kl[(n * 16 + lo) * 72 + hi * 8];
      f32x4 s = __builtin_amdgcn_mfma_f32_16x16x32_bf16(qf0, *(const bf16x8*)kp, zero, 0, 0, 0);
      s = __builtin_amdgcn_mfma_f32_16x16x32_bf16(qf1, *(const bf16x8*)(kp + 32), s, 0, 0, 0);
#pragma unroll
      for (int r = 0; r < 4; ++r) acc[n][r] += fexp2(s[r] - mr[r]) * li[r];
    }
    __syncthreads();
  }
  const float s16 = 1.0f / 16.0f;
#pragma unroll
  for (int n = 0; n < 16; ++n)
#pragma unroll
    for (int r = 0; r < 4; ++r)
      avg[((size_t)(b * 2048 + qrow_base + r)) * 2048 + kbase + n * 16 + lo] = acc[n][r] * s16;
}

extern "C" void kernel_launch(void* const* d_in, const int* in_sizes, int n_in,
                              void* d_out, int out_size, void* d_ws, size_t ws_size,
                              hipStream_t stream) {
  const float* query = (const float*)d_in[0];
  const float* Wqkv  = (const float*)d_in[1];
  const float* bqkv  = (const float*)d_in[2];
  const float* Wo    = (const float*)d_in[3];
  const float* bo    = (const float*)d_in[4];
  float* out = (float*)d_out;
  float* avg = out + (size_t)4096 * 1024;

  char* ws = (char*)d_ws;
  // region A [0,8M): qbf (cvt -> gemm1), then ctx (flash -> gemm3)
  u16* qbf    = (u16*)(ws);
  u16* ctx_ws = (u16*)(ws);
  // region B [8M,14M): wqkvbf (cvt -> gemm1), then m/linv (flash -> avg)
  u16*   wqkvbf  = (u16*)(ws + 8388608);
  float* m_ws    = (float*)(ws + 8388608);
  float* linv_ws = (float*)(ws + 8388608 + 262144);
  u16* wobf  = (u16*)(ws + 14680064);
  u16* q_ws  = (u16*)(ws + 16777216);
  u16* k_ws  = (u16*)(ws + 25165824);
  u16* vt_ws = (u16*)(ws + 33554432);  // ends at 41,943,040 bytes

  k_cvt<<<dim3(4096), dim3(256), 0, stream>>>(query, qbf, 1048576);
  k_cvt<<<dim3(3072), dim3(256), 0, stream>>>(Wqkv, wqkvbf, 786432);
  k_cvt<<<dim3(1024), dim3(256), 0, stream>>>(Wo, wobf, 262144);
  k_gemm_nt<1><<<dim3(24, 32), dim3(256), 0, stream>>>(
      qbf, wqkvbf, bqkv, nullptr, q_ws, k_ws, vt_ws);
  k_flash<<<dim3(16, 32), dim3(256), 0, stream>>>(
      q_ws, k_ws, vt_ws, ctx_ws, m_ws, linv_ws);
  k_avg<<<dim3(8, 32, 2), dim3(256), 0, stream>>>(
      q_ws, k_ws, m_ws, linv_ws, avg);
  k_gemm_nt<0><<<dim3(8, 32), dim3(256), 0, stream>>>(
      ctx_ws, wobf, bo, out, nullptr, nullptr, nullptr);
}

// Round 4
// 166.992 us; speedup vs baseline: 1.6280x; 1.1862x over previous
//
#include <hip/hip_runtime.h>
#include <stdint.h>

typedef unsigned short u16;
typedef __bf16 bf16x8 __attribute__((ext_vector_type(8)));
typedef float f32x4 __attribute__((ext_vector_type(4)));
typedef float f32x16 __attribute__((ext_vector_type(16)));

// fp32 -> bf16 round-to-nearest-even (bit-level)
__device__ __forceinline__ u16 f2b(float f) {
  unsigned u = __builtin_bit_cast(unsigned, f);
  u += 0x7fffu + ((u >> 16) & 1u);
  return (u16)(u >> 16);
}

__device__ __forceinline__ float fexp2(float x) { return __builtin_amdgcn_exp2f(x); }

// async global->LDS, 16B per lane; LDS dest is wave-uniform base + lane*16
__device__ __forceinline__ void gld_lds16(const void* g, void* l) {
  __builtin_amdgcn_global_load_lds((const __attribute__((address_space(1))) unsigned int*)g,
                                   (__attribute__((address_space(3))) unsigned int*)l,
                                   16, 0, 0);
}

__global__ __launch_bounds__(256) void k_cvt(const float* __restrict__ s,
                                             u16* __restrict__ d, int n4) {
  int i = blockIdx.x * 256 + threadIdx.x;
  if (i >= n4) return;
  float4 v = reinterpret_cast<const float4*>(s)[i];
  ushort4 o;
  o.x = f2b(v.x); o.y = f2b(v.y); o.z = f2b(v.z); o.w = f2b(v.w);
  reinterpret_cast<ushort4*>(d)[i] = o;
}

// C = A(MxK) * B(NxK)^T, bf16 in, K=1024, 128x128 tile, BK=32, 256 thr / 4 waves.
// EPI==1: qkv epilogue (bias, q-scale incl. log2e, scatter to q_ws/k_ws/vt_ws)
// EPI==0: out epilogue (bias, fp32 write to outF)
template <int EPI>
__global__ __launch_bounds__(256) void k_gemm_nt(
    const u16* __restrict__ A, const u16* __restrict__ B, const float* __restrict__ bias,
    float* __restrict__ outF, u16* __restrict__ q_ws, u16* __restrict__ k_ws,
    u16* __restrict__ vt_ws) {
  __shared__ u16 Al[2][4096];
  __shared__ u16 Bl[2][4096];
  const int tid = threadIdx.x;
  const int w = tid >> 6, lane = tid & 63;
  const int wr = w >> 1, wc = w & 1;
  const int lo = lane & 15, hi = lane >> 4;
  const int tm = blockIdx.y, tn = blockIdx.x;
  const size_t arow0 = (size_t)tm * 128;
  const size_t brow0 = (size_t)tn * 128;

  f32x4 acc[4][4] = {};

  const int rr = lane >> 2;
  const int kc = (lane & 3) * 8;

  // prologue stage of k-tile 0
  {
    const int k0 = kc;
    for (int rs = 0; rs < 2; ++rs) {
      int seg = rs * 4 + w;
      gld_lds16(A + (arow0 + seg * 16 + rr) * 1024 + k0, &Al[0][seg * 512 + lane * 8]);
      gld_lds16(B + (brow0 + seg * 16 + rr) * 1024 + k0, &Bl[0][seg * 512 + lane * 8]);
    }
  }
  __syncthreads();
  int cur = 0;
  for (int kb = 0; kb < 32; ++kb) {
    if (kb + 1 < 32) {
      const int k0 = (kb + 1) * 32 + kc;
      for (int rs = 0; rs < 2; ++rs) {
        int seg = rs * 4 + w;
        gld_lds16(A + (arow0 + seg * 16 + rr) * 1024 + k0, &Al[cur ^ 1][seg * 512 + lane * 8]);
        gld_lds16(B + (brow0 + seg * 16 + rr) * 1024 + k0, &Bl[cur ^ 1][seg * 512 + lane * 8]);
      }
    }
    bf16x8 af[4], bfr[4];
#pragma unroll
    for (int m = 0; m < 4; ++m)
      af[m] = *(const bf16x8*)&Al[cur][(wr * 64 + m * 16 + lo) * 32 + hi * 8];
#pragma unroll
    for (int n = 0; n < 4; ++n)
      bfr[n] = *(const bf16x8*)&Bl[cur][(wc * 64 + n * 16 + lo) * 32 + hi * 8];
#pragma unroll
    for (int m = 0; m < 4; ++m)
#pragma unroll
      for (int n = 0; n < 4; ++n)
        acc[m][n] = __builtin_amdgcn_mfma_f32_16x16x32_bf16(af[m], bfr[n], acc[m][n], 0, 0, 0);
    __syncthreads();  // drains vmcnt (staged tile ready) + all waves done with cur
    cur ^= 1;
  }

  if (EPI == 0) {
#pragma unroll
    for (int n = 0; n < 4; ++n) {
      const int col = tn * 128 + wc * 64 + n * 16 + lo;
      const float bb = bias[col];
#pragma unroll
      for (int m = 0; m < 4; ++m)
#pragma unroll
        for (int r = 0; r < 4; ++r) {
          const int row = tm * 128 + wr * 64 + m * 16 + hi * 4 + r;
          outF[(size_t)row * 1024 + col] = acc[m][n][r] + bb;
        }
    }
  } else {
    const int sec = tn >> 3;  // block-uniform: 0=q, 1=k, 2=v
#pragma unroll
    for (int n = 0; n < 4; ++n) {
      const int cin = (tn & 7) * 128 + wc * 64 + n * 16 + lo;
      const int h = cin >> 6, d = cin & 63;
      const float bb = bias[sec * 1024 + cin];
#pragma unroll
      for (int m = 0; m < 4; ++m) {
        const int rowb = tm * 128 + wr * 64 + m * 16 + hi * 4;
        const int t0 = rowb >> 1;  // always even
        const float v0 = acc[m][n][0] + bb, v1 = acc[m][n][1] + bb;
        const float v2 = acc[m][n][2] + bb, v3 = acc[m][n][3] + bb;
        if (sec == 0) {
          // q: scale by 1/sqrt(64) * log2(e) so softmax runs in exp2 domain
          const float s = 0.18033688f;
          q_ws[(((size_t)h * 2048 + t0) * 64) + d]            = f2b(v0 * s);   // b=0
          q_ws[(((size_t)(16 + h) * 2048 + t0) * 64) + d]     = f2b(v1 * s);   // b=1
          q_ws[(((size_t)h * 2048 + t0 + 1) * 64) + d]        = f2b(v2 * s);
          q_ws[(((size_t)(16 + h) * 2048 + t0 + 1) * 64) + d] = f2b(v3 * s);
        } else if (sec == 1) {
          k_ws[(((size_t)h * 2048 + t0) * 64) + d]            = f2b(v0);
          k_ws[(((size_t)(16 + h) * 2048 + t0) * 64) + d]     = f2b(v1);
          k_ws[(((size_t)h * 2048 + t0 + 1) * 64) + d]        = f2b(v2);
          k_ws[(((size_t)(16 + h) * 2048 + t0 + 1) * 64) + d] = f2b(v3);
        } else {
          // V^T with key index bit2<->bit3 swapped (matches flash PV layout).
          // t0 even => swap(t0+1) == swap(t0)+1 => paired 4B stores.
          const int tp0 = (t0 & ~12) | ((t0 & 4) << 1) | ((t0 & 8) >> 1);
          ushort2 p0, p1;
          p0.x = f2b(v0); p0.y = f2b(v2);
          p1.x = f2b(v1); p1.y = f2b(v3);
          *(ushort2*)(vt_ws + ((size_t)h * 64 + d) * 2048 + tp0) = p0;
          *(ushort2*)(vt_ws + ((size_t)(16 + h) * 64 + d) * 2048 + tp0) = p1;
        }
      }
    }
  }
}

// Flash attention fwd, swapped-QK^T 32x32 structure (m214-style), exp2 domain.
// wg = 256 thr = 4 warps; warp owns 32 q rows; wg covers 128 q rows.
// Emits ctx (bf16, [T*B][E]) and c_ws[bh][q] = linv * 2^{-m} for k_avg.
__global__ __launch_bounds__(256) void k_flash(
    const u16* __restrict__ q_ws, const u16* __restrict__ k_ws, const u16* __restrict__ vt_ws,
    u16* __restrict__ ctx_ws, float* __restrict__ c_ws) {
  __shared__ __align__(16) u16 KVl[8192];  // [0,4096): K [64 key][64 d]; [4096,8192): V^T — XOR-swizzled
  u16* Kl = KVl;
  u16* Vl = KVl + 4096;
  const int tid = threadIdx.x, w = tid >> 6, lane = tid & 63;
  const int h = lane >> 5, l31 = lane & 31, l7 = lane & 7;
  const int bh = blockIdx.y;
  const int b = bh >> 4, head = bh & 15;
  const int qbase = blockIdx.x * 128;
  const int qrow = qbase + w * 32 + l31;

  // hoist Q fragments (B-operand): qf[j] = Q[qrow][j*16 + h*8 .. +7]
  bf16x8 qf[4];
#pragma unroll
  for (int j = 0; j < 4; ++j)
    qf[j] = *(const bf16x8*)(q_ws + ((size_t)bh * 2048 + qrow) * 64 + j * 16 + h * 8);

  // staging: 2 K-chunks + 2 V-chunks of 16B per thread, swizzled LDS dest
  const int c0 = tid, c1 = tid + 256;
  const int r0 = c0 >> 3, cc0 = c0 & 7;
  const int r1 = c1 >> 3, cc1 = c1 & 7;
  const u16* kg0 = k_ws + ((size_t)bh * 2048 + r0) * 64 + cc0 * 8;
  const u16* kg1 = k_ws + ((size_t)bh * 2048 + r1) * 64 + cc1 * 8;
  const u16* vg0 = vt_ws + ((size_t)bh * 64 + r0) * 2048 + cc0 * 8;
  const u16* vg1 = vt_ws + ((size_t)bh * 64 + r1) * 2048 + cc1 * 8;
  char* kl0 = (char*)Kl + r0 * 128 + ((cc0 ^ (r0 & 7)) * 16);
  char* kl1 = (char*)Kl + r1 * 128 + ((cc1 ^ (r1 & 7)) * 16);
  char* vl0 = (char*)Vl + r0 * 128 + ((cc0 ^ (r0 & 7)) * 16);
  char* vl1 = (char*)Vl + r1 * 128 + ((cc1 ^ (r1 & 7)) * 16);

  f32x16 ca0 = {}, ca1 = {};
  float mrow = -1e30f, lrow = 0.f;

  // T14 async-stage: tile-0 loads issued before the loop
  uint4 ka = *(const uint4*)kg0;
  uint4 kb = *(const uint4*)kg1;
  uint4 va = *(const uint4*)vg0;
  uint4 vb = *(const uint4*)vg1;

  for (int kt = 0; kt < 32; ++kt) {
    __syncthreads();  // previous tile's LDS reads done
    *(uint4*)kl0 = ka; *(uint4*)kl1 = kb;
    *(uint4*)vl0 = va; *(uint4*)vl1 = vb;
    if (kt < 31) {  // issue next tile's loads; latency hides under compute
      ka = *(const uint4*)(kg0 + (size_t)(kt + 1) * 4096);
      kb = *(const uint4*)(kg1 + (size_t)(kt + 1) * 4096);
      va = *(const uint4*)(vg0 + (kt + 1) * 64);
      vb = *(const uint4*)(vg1 + (kt + 1) * 64);
    }
    __syncthreads();  // staged tile visible

    // QK^T swapped: st holds S^T[key][q = l31] in exp2 domain
    f32x16 st0 = {}, st1 = {};
#pragma unroll
    for (int j = 0; j < 4; ++j) {
      bf16x8 k0 = *(const bf16x8*)((const char*)Kl + l31 * 128 + (((2 * j + h) ^ l7) * 16));
      bf16x8 k1 = *(const bf16x8*)((const char*)Kl + (32 + l31) * 128 + (((2 * j + h) ^ l7) * 16));
      st0 = __builtin_amdgcn_mfma_f32_32x32x16_bf16(k0, qf[j], st0, 0, 0, 0);
      st1 = __builtin_amdgcn_mfma_f32_32x32x16_bf16(k1, qf[j], st1, 0, 0, 0);
    }

    // tree max (depth 5, max3-fusable)
    float t8[8];
#pragma unroll
    for (int r = 0; r < 8; ++r)
      t8[r] = fmaxf(fmaxf(st0[r], st0[r + 8]), fmaxf(st1[r], st1[r + 8]));
    float t4a = fmaxf(t8[0], t8[4]), t4b = fmaxf(t8[1], t8[5]);
    float t4c = fmaxf(t8[2], t8[6]), t4d = fmaxf(t8[3], t8[7]);
    float pm = fmaxf(fmaxf(t4a, t4b), fmaxf(t4c, t4d));
    pm = fmaxf(pm, __shfl_xor(pm, 32, 64));

    // T13 defer-max: rescale only when the running max grows by > 8 (log2 units)
    if (!__all(pm <= mrow + 8.0f)) {
      const float nm = fmaxf(mrow, pm);
      const float sc = fexp2(mrow - nm);
      mrow = nm;
      lrow *= sc;
#pragma unroll
      for (int r = 0; r < 16; ++r) { ca0[r] *= sc; ca1[r] *= sc; }
    }

    float ps = 0.f;
#pragma unroll
    for (int r = 0; r < 16; ++r) { float p = fexp2(st0[r] - mrow); st0[r] = p; ps += p; }
#pragma unroll
    for (int r = 0; r < 16; ++r) { float p = fexp2(st1[r] - mrow); st1[r] = p; ps += p; }
    ps += __shfl_xor(ps, 32, 64);
    lrow += ps;

    // pack P^T -> bf16 B-frags (native casts -> v_cvt_pk_bf16_f32); zero cross-lane
    bf16x8 pb00, pb01, pb10, pb11;
#pragma unroll
    for (int i = 0; i < 8; ++i) {
      pb00[i] = (__bf16)st0[i];
      pb01[i] = (__bf16)st0[8 + i];
      pb10[i] = (__bf16)st1[i];
      pb11[i] = (__bf16)st1[8 + i];
    }

    // PV: ctx^T[dh*32 + rho][q] += V^T x P^T  (V key order pre-permuted bit2<->3)
#pragma unroll
    for (int t2 = 0; t2 < 2; ++t2)
#pragma unroll
      for (int kp = 0; kp < 2; ++kp) {
        const int ch = (4 * t2 + 2 * kp + h) ^ l7;
        bf16x8 v0 = *(const bf16x8*)((const char*)Vl + l31 * 128 + ch * 16);
        bf16x8 v1 = *(const bf16x8*)((const char*)Vl + (32 + l31) * 128 + ch * 16);
        const bf16x8 pv = (t2 == 0) ? (kp == 0 ? pb00 : pb01) : (kp == 0 ? pb10 : pb11);
        ca0 = __builtin_amdgcn_mfma_f32_32x32x16_bf16(v0, pv, ca0, 0, 0, 0);
        ca1 = __builtin_amdgcn_mfma_f32_32x32x16_bf16(v1, pv, ca1, 0, 0, 0);
      }
  }

  const float inv = 1.0f / lrow;
  if (lane < 32) {
    // c = linv * 2^{-m}: single normalization constant for k_avg (exp2(s)*c)
    c_ws[(size_t)bh * 2048 + qrow] = inv * fexp2(-mrow);
  }

  // epilogue: transpose ctx^T -> ctx via reused LDS (warp-private 4KB region)
  __syncthreads();  // all warps done with K/V tiles
  u16* tw = KVl + w * 2048;
#pragma unroll
  for (int r = 0; r < 16; ++r) {
    const int d0 = (r & 3) + 8 * (r >> 2) + 4 * h;
    const int d1 = 32 + d0;
    *(u16*)((char*)tw + l31 * 128 + ((2 * d0) ^ (l7 << 4))) = f2b(ca0[r] * inv);
    *(u16*)((char*)tw + l31 * 128 + ((2 * d1) ^ (l7 << 4))) = f2b(ca1[r] * inv);
  }
  __syncthreads();
#pragma unroll
  for (int it = 0; it < 4; ++it) {
    const int row = it * 8 + (lane >> 3);
    uint4 val = *(const uint4*)((const char*)tw + row * 128 + (((lane & 7) ^ (row & 7)) * 16));
    const int q = qbase + w * 32 + row;
    *(uint4*)(ctx_ws + ((size_t)(q * 2 + b)) * 1024 + head * 64 + (lane & 7) * 8) = val;
  }
}

// avg_weights: wg owns (b, 64 q-rows, 128 k-cols); loops 16 heads serially with
// double-buffered reg->LDS staging; S via MFMA (exp2 domain); p = exp2(s)*c.
__global__ __launch_bounds__(256) void k_avg(
    const u16* __restrict__ q_ws, const u16* __restrict__ k_ws,
    const float* __restrict__ c_ws, float* __restrict__ avg) {
  __shared__ __align__(16) u16 Kl[2][128 * 64];  // XOR-swizzled [key][d]
  const int tid = threadIdx.x, w = tid >> 6, lane = tid & 63;
  const int lo = lane & 15, hi = lane >> 4;
  const int kbase = blockIdx.x * 128;
  const int qb = blockIdx.y * 64;
  const int b = blockIdx.z;
  const int qrow = qb + w * 16 + lo;           // B-operand row for Q loads
  const int qrow_base = qb + w * 16 + hi * 4;  // C-layout rows

  // staging: 4 x 16B per thread per head; rows r0+32j, fixed chunk c0
  const int r0 = tid >> 3, c0 = tid & 7;
  const int ldsoff = r0 * 128 + ((c0 ^ (r0 & 7)) << 4);
  const u16* kg = k_ws + ((size_t)(b * 16) * 2048 + kbase + r0) * 64 + c0 * 8;
  const int l7 = lo & 7;

  float acc[8][4] = {};
  const f32x4 zero = {0.f, 0.f, 0.f, 0.f};

  // prologue: head 0
  uint4 rg0 = *(const uint4*)(kg);
  uint4 rg1 = *(const uint4*)(kg + 32 * 64);
  uint4 rg2 = *(const uint4*)(kg + 64 * 64);
  uint4 rg3 = *(const uint4*)(kg + 96 * 64);
  {
    char* dst = (char*)Kl[0] + ldsoff;
    *(uint4*)(dst) = rg0;
    *(uint4*)(dst + 32 * 128) = rg1;
    *(uint4*)(dst + 64 * 128) = rg2;
    *(uint4*)(dst + 96 * 128) = rg3;
  }
  __syncthreads();

  int cur = 0;
  for (int h = 0; h < 16; ++h) {
    const int bh = b * 16 + h;
    if (h + 1 < 16) {  // issue next head's loads; latency hides under compute
      const u16* kgn = kg + (size_t)(h + 1) * 2048 * 64;
      rg0 = *(const uint4*)(kgn);
      rg1 = *(const uint4*)(kgn + 32 * 64);
      rg2 = *(const uint4*)(kgn + 64 * 64);
      rg3 = *(const uint4*)(kgn + 96 * 64);
    }
    const u16* qp = q_ws + ((size_t)bh * 2048 + qrow) * 64 + hi * 8;
    bf16x8 qf0 = *(const bf16x8*)qp;
    bf16x8 qf1 = *(const bf16x8*)(qp + 32);
    const float4 cf = *(const float4*)(c_ws + (size_t)bh * 2048 + qrow_base);
    const float cfa[4] = {cf.x, cf.y, cf.z, cf.w};
    const char* kbse = (const char*)Kl[cur];
#pragma unroll
    for (int n = 0; n < 8; ++n) {
      const char* kp = kbse + (n * 16 + lo) * 128;
      bf16x8 k0 = *(const bf16x8*)(kp + ((hi ^ l7) << 4));
      bf16x8 k1 = *(const bf16x8*)(kp + (((hi + 4) ^ l7) << 4));
      f32x4 s = __builtin_amdgcn_mfma_f32_16x16x32_bf16(qf0, k0, zero, 0, 0, 0);
      s = __builtin_amdgcn_mfma_f32_16x16x32_bf16(qf1, k1, s, 0, 0, 0);
#pragma unroll
      for (int r = 0; r < 4; ++r) acc[n][r] += fexp2(s[r]) * cfa[r];
    }
    if (h + 1 < 16) {
      char* dst = (char*)Kl[cur ^ 1] + ldsoff;
      *(uint4*)(dst) = rg0;
      *(uint4*)(dst + 32 * 128) = rg1;
      *(uint4*)(dst + 64 * 128) = rg2;
      *(uint4*)(dst + 96 * 128) = rg3;
      __syncthreads();
    }
    cur ^= 1;
  }

  const float s16 = 1.0f / 16.0f;
#pragma unroll
  for (int n = 0; n < 8; ++n)
#pragma unroll
    for (int r = 0; r < 4; ++r)
      avg[((size_t)(b * 2048 + qrow_base + r)) * 2048 + kbase + n * 16 + lo] = acc[n][r] * s16;
}

extern "C" void kernel_launch(void* const* d_in, const int* in_sizes, int n_in,
                              void* d_out, int out_size, void* d_ws, size_t ws_size,
                              hipStream_t stream) {
  const float* query = (const float*)d_in[0];
  const float* Wqkv  = (const float*)d_in[1];
  const float* bqkv  = (const float*)d_in[2];
  const float* Wo    = (const float*)d_in[3];
  const float* bo    = (const float*)d_in[4];
  float* out = (float*)d_out;
  float* avg = out + (size_t)4096 * 1024;

  char* ws = (char*)d_ws;
  // region A [0,8M): qbf (cvt -> gemm1), then ctx (flash -> gemm3)
  u16* qbf    = (u16*)(ws);
  u16* ctx_ws = (u16*)(ws);
  // region B [8M,14M): wqkvbf (cvt -> gemm1), then c_ws (flash -> avg)
  u16*   wqkvbf = (u16*)(ws + 8388608);
  float* c_ws   = (float*)(ws + 8388608);
  u16* wobf  = (u16*)(ws + 14680064);
  u16* q_ws  = (u16*)(ws + 16777216);
  u16* k_ws  = (u16*)(ws + 25165824);
  u16* vt_ws = (u16*)(ws + 33554432);  // ends at 41,943,040 bytes

  k_cvt<<<dim3(4096), dim3(256), 0, stream>>>(query, qbf, 1048576);
  k_cvt<<<dim3(3072), dim3(256), 0, stream>>>(Wqkv, wqkvbf, 786432);
  k_cvt<<<dim3(1024), dim3(256), 0, stream>>>(Wo, wobf, 262144);
  k_gemm_nt<1><<<dim3(24, 32), dim3(256), 0, stream>>>(
      qbf, wqkvbf, bqkv, nullptr, q_ws, k_ws, vt_ws);
  k_flash<<<dim3(16, 32), dim3(256), 0, stream>>>(
      q_ws, k_ws, vt_ws, ctx_ws, c_ws);
  k_avg<<<dim3(16, 32, 2), dim3(256), 0, stream>>>(
      q_ws, k_ws, c_ws, avg);
  k_gemm_nt<0><<<dim3(8, 32), dim3(256), 0, stream>>>(
      ctx_ws, wobf, bo, out, nullptr, nullptr, nullptr);
}